// Round 10
// baseline (103.277 us; speedup 1.0000x reference)
//
#include <hip/hip_runtime.h>
#include <math.h>

#define N_NODES 8192
#define N_EDGES 262144
#define NFEAT 128
#define NHID 256
#define NCLASS 16

// f32 -> bf16 with round-to-nearest-even
__device__ inline unsigned int f2bf(float f) {
    unsigned int u = __float_as_uint(f);
    u += 0x7fffu + ((u >> 16) & 1u);
    return u >> 16;
}

#define CVT4(v, f) { \
    f[0] = __uint_as_float((v).x << 16); f[1] = __uint_as_float((v).x & 0xffff0000u); \
    f[2] = __uint_as_float((v).y << 16); f[3] = __uint_as_float((v).y & 0xffff0000u); }

// ---------------- zero deg + counts (contiguous 64 KB) ----------------
__global__ void zero_kernel(int* __restrict__ p) {
    int i = blockIdx.x * blockDim.x + threadIdx.x;   // 16384 words
    p[i] = 0;
}

// ---------------- blocks [0,1024): histogram+deg; [1024,1536): x -> bf16 ----------------
__global__ __launch_bounds__(256) void histcvt_kernel(const int* __restrict__ ei,
                                                      const float* __restrict__ ew,
                                                      const float* __restrict__ x,
                                                      float* __restrict__ deg,
                                                      int* __restrict__ counts,
                                                      uint4* __restrict__ xb4) {
    int t = threadIdx.x;
    int b = blockIdx.x;
    if (b < 1024) {
        int e = b * 256 + t;                  // 1024*256 == E exactly
        int r = ei[e];
        atomicAdd(&deg[r], ew[e]);
        atomicAdd(&counts[r], 1);
    } else {
        int idx = ((b - 1024) * 256 + t) * 8; // 512*256*8 == N*NFEAT exactly
        float4 a = ((const float4*)(x + idx))[0];
        float4 c = ((const float4*)(x + idx))[1];
        uint4 o;
        o.x = f2bf(a.x) | (f2bf(a.y) << 16);
        o.y = f2bf(a.z) | (f2bf(a.w) << 16);
        o.z = f2bf(c.x) | (f2bf(c.y) << 16);
        o.w = f2bf(c.z) | (f2bf(c.w) << 16);
        xb4[idx >> 3] = o;
    }
}

// ---------------- scan of PADDED counts + dinv + pad-entry fill (single block) ----------------
// Rows padded to multiple of 8 so the gather inner loops have fixed trip count.
// Pad entries are (col=r, w=0): exact no-ops in the accumulation.
__global__ __launch_bounds__(1024) void scan_kernel(const int* __restrict__ counts,
                                                    const float* __restrict__ deg,
                                                    int* __restrict__ rowstart,
                                                    int* __restrict__ cur,
                                                    float* __restrict__ dinv,
                                                    int2* __restrict__ colw) {
    __shared__ int wsum[16];
    __shared__ int woff[16];
    int t = threadIdx.x;              // 0..1023, each handles 8 rows
    int base = t * 8;
    int vals[8], cnt[8];
    int s = 0;
    #pragma unroll
    for (int i = 0; i < 8; ++i) {
        vals[i] = s;
        cnt[i] = counts[base + i];
        s += (cnt[i] + 7) & ~7;                    // padded size
        float d = deg[base + i] + 1.0f;            // + self loop, always >= 1
        dinv[base + i] = 1.0f / sqrtf(d);
    }
    int lane = t & 63, wave = t >> 6;
    int sc = s;  // inclusive wave scan of per-thread totals
    #pragma unroll
    for (int off = 1; off < 64; off <<= 1) {
        int u = __shfl_up(sc, off);
        if (lane >= off) sc += u;
    }
    if (lane == 63) wsum[wave] = sc;
    __syncthreads();
    if (t == 0) { int a = 0; for (int i = 0; i < 16; ++i) { woff[i] = a; a += wsum[i]; } }
    __syncthreads();
    int texcl = sc - s + woff[wave];
    #pragma unroll
    for (int i = 0; i < 8; ++i) {
        int st = texcl + vals[i];
        rowstart[base + i] = st;
        cur[base + i] = st;           // scatter's running cursor starts at rowstart
        int pe = st + ((cnt[i] + 7) & ~7);
        for (int p = st + cnt[i]; p < pe; ++p)
            colw[p] = make_int2(base + i, 0);      // zero-weight self pad
    }
    if (t == 1023) rowstart[N_NODES] = texcl + s;
}

// ---------------- scatter edges into CSR order, weight pre-normalized ----------------
// w' = w * dinv[r] * dinv[c]; packed with col into one 8B store.
__global__ void scatter_kernel(const int* __restrict__ ei, const float* __restrict__ ew,
                               const float* __restrict__ dinv,
                               int* __restrict__ cur, int2* __restrict__ colw, int E) {
    int e = blockIdx.x * blockDim.x + threadIdx.x;
    if (e < E) {
        int r = ei[e];
        int c = ei[E + e];
        int pos = atomicAdd(&cur[r], 1);
        float w = ew[e] * dinv[r] * dinv[c];
        colw[pos] = make_int2(c, __float_as_int(w));
    }
}

// ---------------- fused: AX-tile (bf16 gather) -> H = relu(AX@W1+b1) -> V2 = H@W2 ----------------
// 8 rows/block, 1024 blocks, 32 lanes/row. LDS ~13.2 KB -> 8 blocks/CU.
// Rows are padded to x8: inner gather loop is a fixed, fully-unrolled 8 chunk.
__global__ __launch_bounds__(256) void layer12_kernel(const int* __restrict__ rowstart,
                                                      const int2* __restrict__ colw,
                                                      const uint2* __restrict__ xb2,
                                                      const float* __restrict__ dinv,
                                                      const float* __restrict__ W1,
                                                      const float* __restrict__ b1,
                                                      const float* __restrict__ W2,
                                                      float* __restrict__ V2) {
    __shared__ float axs[8][NFEAT];        // 4 KB
    __shared__ float hs[8][NHID + 4];      // 8.125 KB (+4 pad)
    __shared__ float part[256];            // 1 KB
    int t = threadIdx.x;

    // ---- phase A: AX[r] = dinv[r]^2 x[r] + sum w' x[c]; 32 lanes/row, 4 bf16/lane
    int lane = t & 31;
    int rloc = t >> 5;
    int r = blockIdx.x * 8 + rloc;
    int s = rowstart[r], e = rowstart[r + 1];   // e - s is a multiple of 8
    float di = dinv[r];
    float c0 = di * di;
    uint2 xv = xb2[r * 32 + lane];
    float xf[4]; CVT4(xv, xf);
    float acc[4];
    #pragma unroll
    for (int i = 0; i < 4; ++i) acc[i] = c0 * xf[i];
    for (int base = s; base < e; base += 8) {
        int2 cw = colw[base + (lane & 7)];
        #pragma unroll
        for (int u = 0; u < 8; ++u) {
            int c = __shfl(cw.x, u, 8);
            float w = __int_as_float(__shfl(cw.y, u, 8));
            uint2 v = xb2[c * 32 + lane];
            float vf[4]; CVT4(v, vf);
            #pragma unroll
            for (int i = 0; i < 4; ++i) acc[i] += w * vf[i];
        }
    }
    ((float4*)&axs[rloc][lane * 4])[0] = make_float4(acc[0], acc[1], acc[2], acc[3]);
    __syncthreads();

    // ---- phase B: hs[q][t] = relu(sum_k axs[q][k] * W1[k][t] + b1[t]); t = column
    float hacc[8];
    #pragma unroll
    for (int q = 0; q < 8; ++q) hacc[q] = 0.0f;
    #pragma unroll 4
    for (int k = 0; k < NFEAT; ++k) {
        float w = W1[k * NHID + t];
        #pragma unroll
        for (int q = 0; q < 8; ++q) hacc[q] += axs[q][k] * w;
    }
    float bb = b1[t];
    #pragma unroll
    for (int q = 0; q < 8; ++q) {
        float v = hacc[q] + bb;
        hs[q][t] = v > 0.0f ? v : 0.0f;
    }
    __syncthreads();

    // ---- phase C: V2[r][j] = sum_k hs[r][k] * W2[k][j]; W2 via L1/L2 (16 KB, hot)
    int j = t & 15;
    int rq = (t >> 4) & 7;
    int kb = (t >> 7) * 128;
    float p = 0.0f;
    #pragma unroll 8
    for (int k = 0; k < 128; ++k) p += hs[rq][kb + k] * W2[(kb + k) * NCLASS + j];
    part[t] = p;
    __syncthreads();
    if (t < 128) {
        int rg = blockIdx.x * 8 + (t >> 4);
        V2[rg * NCLASS + (t & 15)] = part[t] + part[t + 128];
    }
}

// ---------------- out[r] = log_softmax(dinv[r]^2*V2[r] + sum w'*V2[c] + b2) ----------------
__global__ __launch_bounds__(256) void agg2_kernel(const int* __restrict__ rowstart,
                                                   const int2* __restrict__ colw,
                                                   const float* __restrict__ V2,
                                                   const float* __restrict__ dinv,
                                                   const float* __restrict__ b2,
                                                   float* __restrict__ out) {
    int t = threadIdx.x;
    int j = t & 15;                   // class
    int r = blockIdx.x * 16 + (t >> 4);
    int s = rowstart[r], e = rowstart[r + 1];   // multiple of 8
    float di = dinv[r];
    float acc = di * di * V2[r * NCLASS + j];
    for (int base = s; base < e; base += 8) {
        int2 cw = colw[base + (j & 7)];
        #pragma unroll
        for (int u = 0; u < 8; ++u) {
            int c = __shfl(cw.x, u, 8);
            float w = __int_as_float(__shfl(cw.y, u, 8));
            acc += w * V2[c * NCLASS + j];
        }
    }
    float v = acc + b2[j];
    // log_softmax across the 16 lanes of this row-group
    float mx = v;
    #pragma unroll
    for (int off = 1; off < 16; off <<= 1) mx = fmaxf(mx, __shfl_xor(mx, off));
    float ex = expf(v - mx);
    float ssum = ex;
    #pragma unroll
    for (int off = 1; off < 16; off <<= 1) ssum += __shfl_xor(ssum, off);
    out[r * NCLASS + j] = v - mx - logf(ssum);
}

extern "C" void kernel_launch(void* const* d_in, const int* in_sizes, int n_in,
                              void* d_out, int out_size, void* d_ws, size_t ws_size,
                              hipStream_t stream) {
    const float* x  = (const float*)d_in[0];
    const int*   ei = (const int*)d_in[1];      // [2, E] flat: row = ei[e], col = ei[E+e]
    const float* ew = (const float*)d_in[2];
    const float* W1 = (const float*)d_in[3];
    const float* b1 = (const float*)d_in[4];
    const float* W2 = (const float*)d_in[5];
    const float* b2 = (const float*)d_in[6];
    float* out = (float*)d_out;

    const int E = N_EDGES;
    const int n = N_NODES;

    char* ws = (char*)d_ws;
    float* deg      = (float*)(ws);                       // [0, 32K)
    int*   counts   = (int*)  (ws + 32768);               // [32K, 64K)
    int*   cur      = (int*)  (ws + 65536);               // [64K, 96K) (init by scan)
    float* dinv     = (float*)(ws + 98304);               // [96K, 128K)
    int*   rowstart = (int*)  (ws + 131072);              // [128K, 164K): 8193 ints + pad
    int2*  colw     = (int2*) (ws + 262144);              // [256K, 256K+2.56M) padded CSR
    float* V2       = (float*)(ws + 4194304);             // [4M, 4M+512K)
    uint4* xb4      = (uint4*)(ws + 8388608);             // [8M, 10M): bf16 x

    zero_kernel<<<64, 256, 0, stream>>>((int*)ws);  // deg + counts = 16384 words

    histcvt_kernel<<<1536, 256, 0, stream>>>(ei, ew, x, deg, counts, xb4);
    scan_kernel<<<1, 1024, 0, stream>>>(counts, deg, rowstart, cur, dinv, colw);
    scatter_kernel<<<E / 256, 256, 0, stream>>>(ei, ew, dinv, cur, colw, E);

    layer12_kernel<<<n / 8, 256, 0, stream>>>(rowstart, colw, (const uint2*)xb4,
                                              dinv, W1, b1, W2, V2);
    agg2_kernel<<<n / 16, 256, 0, stream>>>(rowstart, colw, V2, dinv, b2, out);
}

// Round 11
// 59.702 us; speedup vs baseline: 1.7299x; 1.7299x over previous
//
#include <hip/hip_runtime.h>
#include <math.h>

#define N_NODES 8192
#define N_EDGES 262144
#define NFEAT 128
#define NHID 256
#define NCLASS 16
#define ELLS 96   // ELL stride; P(Poisson(32) >= 96) ~ 1e-18 per row

// f32 -> bf16 with round-to-nearest-even
__device__ inline unsigned int f2bf(float f) {
    unsigned int u = __float_as_uint(f);
    u += 0x7fffu + ((u >> 16) & 1u);
    return u >> 16;
}

#define CVT4(v, f) { \
    f[0] = __uint_as_float((v).x << 16); f[1] = __uint_as_float((v).x & 0xffff0000u); \
    f[2] = __uint_as_float((v).y << 16); f[3] = __uint_as_float((v).y & 0xffff0000u); }

// ---------------- zero cnt (32 KB) ----------------
__global__ void zero_kernel(int* __restrict__ p) {
    p[blockIdx.x * 256 + threadIdx.x] = 0;   // 32 blocks x 256 = 8192 words
}

// ---------------- one pass over edges: count + ELL store (raw weight) ----------------
__global__ __launch_bounds__(256) void histscatter_kernel(const int* __restrict__ ei,
                                                          const float* __restrict__ ew,
                                                          int* __restrict__ cnt,
                                                          int2* __restrict__ ell) {
    int e = blockIdx.x * 256 + threadIdx.x;     // 1024 blocks == E exactly
    int r = ei[e];
    int c = ei[N_EDGES + e];
    float w = ew[e];
    int slot = atomicAdd(&cnt[r], 1);
    ell[r * ELLS + slot] = make_int2(c, __float_as_int(w));
}

// ---------------- per row: deg = sum(ell w), dinv = rsqrt(deg+1), xs = bf16(dinv*x) ----------------
// 16 rows/block, 16 lanes/row. No atomics: reads the ELL row it owns.
__global__ __launch_bounds__(256) void dinvcvt_kernel(const int* __restrict__ cnt,
                                                      const int2* __restrict__ ell,
                                                      const float* __restrict__ x,
                                                      float* __restrict__ dinv,
                                                      uint4* __restrict__ xs) {
    int t = threadIdx.x;
    int j = t & 15;
    int r = blockIdx.x * 16 + (t >> 4);
    int n = cnt[r];
    float sum = 0.0f;
    for (int base = 0; base < n; base += 16) {
        int idx = base + j;
        if (idx < n) sum += __int_as_float(ell[r * ELLS + idx].y);
    }
    #pragma unroll
    for (int off = 1; off < 16; off <<= 1) sum += __shfl_xor(sum, off, 16);
    float di = rsqrtf(sum + 1.0f);              // + self loop, always >= 1
    if (j == 0) dinv[r] = di;
    const float4* xp = (const float4*)(x + (size_t)r * NFEAT + j * 8);
    float4 a = xp[0], b = xp[1];
    uint4 o;
    o.x = f2bf(di * a.x) | (f2bf(di * a.y) << 16);
    o.y = f2bf(di * a.z) | (f2bf(di * a.w) << 16);
    o.z = f2bf(di * b.x) | (f2bf(di * b.y) << 16);
    o.w = f2bf(di * b.z) | (f2bf(di * b.w) << 16);
    xs[r * 16 + j] = o;
}

// ---------------- fused: ELL gather on xs -> AX -> H=relu(AX@W1+b1) -> V2s=dinv*(H@W2) ----------------
// 8 rows/block, 1024 blocks, 32 lanes/row. LDS ~13.2 KB -> high occupancy.
__global__ __launch_bounds__(256) void layer12_kernel(const int* __restrict__ cnt,
                                                      const int2* __restrict__ ell,
                                                      const uint2* __restrict__ xs2,
                                                      const float* __restrict__ dinv,
                                                      const float* __restrict__ W1,
                                                      const float* __restrict__ b1,
                                                      const float* __restrict__ W2,
                                                      float* __restrict__ V2s) {
    __shared__ float axs[8][NFEAT];        // 4 KB
    __shared__ float hs[8][NHID + 4];      // 8.125 KB
    __shared__ float part[256];            // 1 KB
    int t = threadIdx.x;

    // ---- phase A: acc = xs[r] + sum w*xs[c]; AX = dinv[r]*acc
    int lane = t & 31;
    int rloc = t >> 5;
    int r = blockIdx.x * 8 + rloc;
    int n = cnt[r];
    float di = dinv[r];
    uint2 xv = xs2[r * 32 + lane];
    float acc[4];
    CVT4(xv, acc);                          // self term (xs already dinv-scaled)
    for (int base = 0; base < n; base += 8) {
        int2 cw = ell[r * ELLS + base + (lane & 7)];
        #pragma unroll
        for (int u = 0; u < 8; ++u) {
            int k = base + u;
            int c = __shfl(cw.x, u, 8) & (N_NODES - 1);   // clamp garbage tails
            float w = __int_as_float(__shfl(cw.y, u, 8));
            w = (k < n) ? w : 0.0f;                       // mask tail
            uint2 v = xs2[c * 32 + lane];
            float vf[4]; CVT4(v, vf);
            #pragma unroll
            for (int i = 0; i < 4; ++i) acc[i] += w * vf[i];
        }
    }
    #pragma unroll
    for (int i = 0; i < 4; ++i) acc[i] *= di;
    ((float4*)&axs[rloc][lane * 4])[0] = make_float4(acc[0], acc[1], acc[2], acc[3]);
    __syncthreads();

    // ---- phase B: hs[q][t] = relu(sum_k axs[q][k] * W1[k][t] + b1[t]); t = column
    float hacc[8];
    #pragma unroll
    for (int q = 0; q < 8; ++q) hacc[q] = 0.0f;
    #pragma unroll 4
    for (int k = 0; k < NFEAT; ++k) {
        float w = W1[k * NHID + t];
        #pragma unroll
        for (int q = 0; q < 8; ++q) hacc[q] += axs[q][k] * w;
    }
    float bb = b1[t];
    #pragma unroll
    for (int q = 0; q < 8; ++q) {
        float v = hacc[q] + bb;
        hs[q][t] = v > 0.0f ? v : 0.0f;
    }
    __syncthreads();

    // ---- phase C: V2s[r][j] = dinv[r] * sum_k hs[r][k] * W2[k][j]; W2 via L1/L2
    int j = t & 15;
    int rq = (t >> 4) & 7;
    int kb = (t >> 7) * 128;
    float p = 0.0f;
    #pragma unroll 8
    for (int k = 0; k < 128; ++k) p += hs[rq][kb + k] * W2[(kb + k) * NCLASS + j];
    part[t] = p;
    __syncthreads();
    if (t < 128) {
        int rg = blockIdx.x * 8 + (t >> 4);
        V2s[rg * NCLASS + (t & 15)] = dinv[rg] * (part[t] + part[t + 128]);
    }
}

// ---------------- out[r] = log_softmax(dinv[r]*(V2s[r] + sum w*V2s[c]) + b2) ----------------
__global__ __launch_bounds__(256) void agg2_kernel(const int* __restrict__ cnt,
                                                   const int2* __restrict__ ell,
                                                   const float* __restrict__ V2s,
                                                   const float* __restrict__ dinv,
                                                   const float* __restrict__ b2,
                                                   float* __restrict__ out) {
    int t = threadIdx.x;
    int j = t & 15;                   // class
    int r = blockIdx.x * 16 + (t >> 4);
    int n = cnt[r];
    float di = dinv[r];
    float acc = V2s[r * NCLASS + j];  // self term (V2s already dinv-scaled)
    for (int base = 0; base < n; base += 8) {
        int2 cw = ell[r * ELLS + base + (j & 7)];
        #pragma unroll
        for (int u = 0; u < 8; ++u) {
            int k = base + u;
            int c = __shfl(cw.x, u, 8) & (N_NODES - 1);
            float w = __int_as_float(__shfl(cw.y, u, 8));
            w = (k < n) ? w : 0.0f;
            acc += w * V2s[c * NCLASS + j];
        }
    }
    float v = di * acc + b2[j];
    // log_softmax across the 16 lanes of this row-group
    float mx = v;
    #pragma unroll
    for (int off = 1; off < 16; off <<= 1) mx = fmaxf(mx, __shfl_xor(mx, off));
    float ex = expf(v - mx);
    float ssum = ex;
    #pragma unroll
    for (int off = 1; off < 16; off <<= 1) ssum += __shfl_xor(ssum, off);
    out[r * NCLASS + j] = v - mx - logf(ssum);
}

extern "C" void kernel_launch(void* const* d_in, const int* in_sizes, int n_in,
                              void* d_out, int out_size, void* d_ws, size_t ws_size,
                              hipStream_t stream) {
    const float* x  = (const float*)d_in[0];
    const int*   ei = (const int*)d_in[1];      // [2, E] flat: row = ei[e], col = ei[E+e]
    const float* ew = (const float*)d_in[2];
    const float* W1 = (const float*)d_in[3];
    const float* b1 = (const float*)d_in[4];
    const float* W2 = (const float*)d_in[5];
    const float* b2 = (const float*)d_in[6];
    float* out = (float*)d_out;

    const int n = N_NODES;

    char* ws = (char*)d_ws;
    int*   cnt  = (int*)  (ws);                  // [0, 32K)
    float* dinv = (float*)(ws + 32768);          // [32K, 64K)
    int2*  ell  = (int2*) (ws + 65536);          // [64K, 64K+6M): 8192*96*8 B
    float* V2s  = (float*)(ws + 8388608);        // [8M, 8.5M)
    uint4* xs   = (uint4*)(ws + 16777216);       // [16M, 18M): bf16 dinv-scaled x

    zero_kernel<<<32, 256, 0, stream>>>(cnt);

    histscatter_kernel<<<N_EDGES / 256, 256, 0, stream>>>(ei, ew, cnt, ell);
    dinvcvt_kernel<<<n / 16, 256, 0, stream>>>(cnt, ell, x, dinv, xs);

    layer12_kernel<<<n / 8, 256, 0, stream>>>(cnt, ell, (const uint2*)xs,
                                              dinv, W1, b1, W2, V2s);
    agg2_kernel<<<n / 16, 256, 0, stream>>>(cnt, ell, V2s, dinv, b2, out);
}